// Round 15
// baseline (218.878 us; speedup 1.0000x reference)
//
#include <hip/hip_runtime.h>

// Morphological dilation2d on MI355X (gfx950).
// out[b,o,h,w] = max_{c,i,j} ( x_zpad[b,c,h+i-2,w+j-2] + weight[o,c,i,j] )
// B=4, C=4, O=4, H=W=1024, K=5, PAD=2, fp32.
//
// Round-15: R14's no-LDS variant with the window-base off-by-two FIXED.
// R14 used gb = tile_w0+tx*4-2, shifting every window +2 columns (absmax 5.5)
// and misaligning the float4 loads. Correct base is -4 (matches the LDS
// version's halo mapping: win[e] <-> col tile_w0+tx*4-4+e, consume
// win[2+p+j] -> out_col+j-2), which is also 16B-aligned.
// Hypothesis (still untested): the LDS machinery itself (staging+barrier
// busy, residency-capped stall gap, 5.24M conflict cycles) is the remaining
// overhead. A block's input slice (~26 KB) fits L1, so window reads go
// straight to global: same vertical reuse via L1/L2, zero staging, zero
// barriers, zero LDS, zero bank conflicts, residency -> wave cap.
// Hot-loop arithmetic byte-identical to R6 (measured best 73.4us).

constexpr int Himg = 1024, Wimg = 1024, Cin = 4, Cout = 4, Kn = 5;
constexpr int TH = 8, TW = 128;     // output tile per 256-thread block
constexpr int NW = Cout * Cin * Kn * Kn;  // 400 weights

typedef float v2f __attribute__((ext_vector_type(2)));

// Device-global scratch: duplicated weight pairs, [c][i][o][j] = {w, w}. 3.2 KB.
__device__ __align__(16) v2f wdup[Cin * Kn * Cout * Kn];

// weight [o][c][i][j] -> wdup[c][i][o][j] = {w, w}
__global__ void reorg_w(const float* __restrict__ w) {
  int idx = threadIdx.x;
  if (idx < NW) {
    int o  = idx / (Cin * Kn * Kn);
    int r  = idx % (Cin * Kn * Kn);
    int c  = r / (Kn * Kn);
    int r2 = r % (Kn * Kn);
    int i  = r2 / Kn, j = r2 % Kn;
    float v = w[idx];
    v2f p; p.x = v; p.y = v;
    wdup[((c * Kn + i) * Cout + o) * Kn + j] = p;
  }
}

// 5-input max folded so LLVM forms v_max3_f32.
__device__ __forceinline__ float max5(float a, float b, float c, float d, float e) {
  return fmaxf(fmaxf(a, b), fmaxf(c, fmaxf(d, e)));
}

__global__ __launch_bounds__(256) void morph(const float* __restrict__ x,
                                             float* __restrict__ out) {
  const int tid = threadIdx.x;
  const int tile_w0 = blockIdx.x * TW;
  const int tile_r0 = blockIdx.y * TH;
  const int b = blockIdx.z;

  const int tx = tid & 31;   // 32 thread-cols x 4 px
  const int ty = tid >> 5;   // 8 rows

  // Window base: win[e] <-> global col gb+e, gb = out_col0 - 4 (16B-aligned).
  const int gb = tile_w0 + tx * 4 - 4;
  const bool colsafe = (gb >= 0) && (gb + 12 <= Wimg);  // false only for lane
                                                        // tx=0 of block-col 0 and
                                                        // tx=31 of the last one

  float acc[Cout][4];
#pragma unroll
  for (int o = 0; o < Cout; ++o)
#pragma unroll
    for (int p = 0; p < 4; ++p) acc[o][p] = -3.4e38f;

// Per output-channel O: 10 packed adds (v_pk_add_f32, SGPR-pair weight operand)
// + 4 x (max5 tree + acc fold). Identical to R6.
#define ACC_O(O, WDP)                                                                     \
  do {                                                                                    \
    v2f p01[5], p23[5];                                                                   \
    _Pragma("unroll") for (int j = 0; j < 5; ++j) {                                       \
      v2f wb = (WDP)[(O) * Kn + j];                                                       \
      p01[j] = a2[j] + wb;                                                                \
      p23[j] = b2[j] + wb;                                                                \
    }                                                                                     \
    acc[O][0] = fmaxf(acc[O][0], max5(p01[0].x, p01[1].x, p01[2].x, p01[3].x, p01[4].x)); \
    acc[O][1] = fmaxf(acc[O][1], max5(p01[0].y, p01[1].y, p01[2].y, p01[3].y, p01[4].y)); \
    acc[O][2] = fmaxf(acc[O][2], max5(p23[0].x, p23[1].x, p23[2].x, p23[3].x, p23[4].x)); \
    acc[O][3] = fmaxf(acc[O][3], max5(p23[0].y, p23[1].y, p23[2].y, p23[3].y, p23[4].y)); \
  } while (0)

#pragma unroll 1
  for (int c = 0; c < Cin; ++c) {
    const float* __restrict__ plane = x + (size_t)(b * Cin + c) * Himg * Wimg;
#pragma unroll
    for (int i = 0; i < Kn; ++i) {
      const int gr = tile_r0 + ty + i - 2;   // wave-uniform row
      float win[12];
#pragma unroll
      for (int e = 0; e < 12; ++e) win[e] = 0.f;

      if ((unsigned)gr < (unsigned)Himg) {
        const float* srcr = plane + (size_t)gr * Wimg;
        if (colsafe) {
          // fast path: 3 aligned global_load_dwordx4, L1-resident reuse
          float4 q0 = *(const float4*)(srcr + gb);
          float4 q1 = *(const float4*)(srcr + gb + 4);
          float4 q2 = *(const float4*)(srcr + gb + 8);
          win[0] = q0.x; win[1]  = q0.y; win[2]  = q0.z; win[3]  = q0.w;
          win[4] = q1.x; win[5]  = q1.y; win[6]  = q1.z; win[7]  = q1.w;
          win[8] = q2.x; win[9]  = q2.y; win[10] = q2.z; win[11] = q2.w;
        } else {
          // slow path: 2 lanes total across the grid's edge block-columns
#pragma unroll
          for (int e = 0; e < 12; ++e) {
            const int col = gb + e;
            if ((unsigned)col < (unsigned)Wimg) win[e] = srcr[col];
          }
        }
      }

      // window pairs, shared across the 4 output channels (as R6)
      v2f a2[5], b2[5];
#pragma unroll
      for (int j = 0; j < 5; ++j) {
        a2[j].x = win[2 + j]; a2[j].y = win[3 + j];
        b2[j].x = win[4 + j]; b2[j].y = win[5 + j];
      }

      // wave-uniform duplicated pairs -> SGPR pairs feeding v_pk_add_f32
      const v2f* wdp = wdup + (c * Kn + i) * Cout * Kn;

      ACC_O(0, wdp);
      ACC_O(1, wdp);
      ACC_O(2, wdp);
      ACC_O(3, wdp);
    }
  }
#undef ACC_O

  // ---- epilogue: float4 stores, coalesced ----
  const int r = tile_r0 + ty;
  const int gc0 = tile_w0 + tx * 4;
#pragma unroll
  for (int o = 0; o < Cout; ++o) {
    float4 res = make_float4(acc[o][0], acc[o][1], acc[o][2], acc[o][3]);
    *(float4*)&out[((size_t)(b * Cout + o) * Himg + r) * Wimg + gc0] = res;
  }
}

extern "C" void kernel_launch(void* const* d_in, const int* in_sizes, int n_in,
                              void* d_out, int out_size, void* d_ws, size_t ws_size,
                              hipStream_t stream) {
  const float* x = (const float*)d_in[0];
  const float* w = (const float*)d_in[1];
  float* out = (float*)d_out;

  reorg_w<<<dim3(1), dim3(512), 0, stream>>>(w);

  dim3 grid(Wimg / TW, Himg / TH, 4);  // (8, 128, 4) = 4096 blocks
  morph<<<grid, dim3(256), 0, stream>>>(x, out);
}